// Round 1
// baseline (1408.050 us; speedup 1.0000x reference)
//
#include <hip/hip_runtime.h>

#define NNODES 40000
#define NEDGES 640000
#define FIN 128
#define HID 512
#define NGRAPH 64

// ---------------- CSR build ----------------

__global__ void k_deg(const int* __restrict__ dst, int* __restrict__ deg) {
    int e = blockIdx.x * 256 + threadIdx.x;
    if (e < NEDGES) atomicAdd(&deg[dst[e]], 1);
}

// single-block scan: thread t serially owns CH contiguous elements, block-scan of partials
__global__ void k_scan(const int* __restrict__ deg, int* __restrict__ off, int* __restrict__ cursor) {
    __shared__ int sh[1024];
    constexpr int CH = (NNODES + 1023) / 1024;  // 40
    int t = threadIdx.x;
    int base = t * CH;
    int vals[CH];
    int local = 0;
#pragma unroll
    for (int i = 0; i < CH; ++i) {
        int idx = base + i;
        int v = (idx < NNODES) ? deg[idx] : 0;
        vals[i] = v;
        local += v;
    }
    sh[t] = local;
    __syncthreads();
    for (int o = 1; o < 1024; o <<= 1) {
        int add = (t >= o) ? sh[t - o] : 0;
        __syncthreads();
        sh[t] += add;
        __syncthreads();
    }
    int run = sh[t] - local;  // exclusive prefix
#pragma unroll
    for (int i = 0; i < CH; ++i) {
        int idx = base + i;
        if (idx < NNODES) {
            off[idx] = run;
            cursor[idx] = run;
            run += vals[i];
        }
    }
    if (t == 1023) off[NNODES] = sh[1023];
}

__global__ void k_fill(const int* __restrict__ src, const int* __restrict__ dst,
                       const float* __restrict__ ew, int* __restrict__ cursor,
                       int* __restrict__ csrc, float* __restrict__ cw) {
    int e = blockIdx.x * 256 + threadIdx.x;
    if (e < NEDGES) {
        int p = atomicAdd(&cursor[dst[e]], 1);
        csrc[p] = src[e];
        cw[p] = ew[e];
    }
}

// ---------------- aggregation (gather form, wave per node) ----------------

__global__ void k_agg128(const float* __restrict__ x, const int* __restrict__ off,
                         const int* __restrict__ csrc, const float* __restrict__ cw,
                         float* __restrict__ out) {
    int node = blockIdx.x * 4 + (threadIdx.x >> 6);
    if (node >= NNODES) return;
    int lane = threadIdx.x & 63;
    float2 acc = {0.f, 0.f};
    int s = off[node], e = off[node + 1];
    for (int k = s; k < e; ++k) {
        int j = csrc[k];
        float w = cw[k];
        float2 a = ((const float2*)(x + (size_t)j * FIN))[lane];
        acc.x += a.x * w;
        acc.y += a.y * w;
    }
    ((float2*)(out + (size_t)node * FIN))[lane] = acc;
}

__global__ void k_agg512(const float* __restrict__ h, const int* __restrict__ off,
                         const int* __restrict__ csrc, const float* __restrict__ cw,
                         float* __restrict__ out) {
    int node = blockIdx.x * 4 + (threadIdx.x >> 6);
    if (node >= NNODES) return;
    int lane = threadIdx.x & 63;
    float4 acc0 = {0, 0, 0, 0}, acc1 = {0, 0, 0, 0};
    int s = off[node], e = off[node + 1];
    for (int k = s; k < e; ++k) {
        int j = csrc[k];
        float w = cw[k];
        const float4* row = (const float4*)(h + (size_t)j * HID);
        float4 a = row[lane];
        float4 b = row[lane + 64];
        acc0.x += a.x * w; acc0.y += a.y * w; acc0.z += a.z * w; acc0.w += a.w * w;
        acc1.x += b.x * w; acc1.y += b.y * w; acc1.z += b.z * w; acc1.w += b.w * w;
    }
    float4* o = (float4*)(out + (size_t)node * HID);
    o[lane] = acc0;
    o[lane + 64] = acc1;
}

// ---------------- dual GEMM: C = relu(A0@W0 + A1@W1 + b), NN = 512 ----------------
// 64x64 tile, 256 threads, 4x4 micro-tile, BK=16.
// POOL: instead of storing C, atomically accumulate rows into psum[batch[row]].

template <bool POOL>
__global__ void k_dualgemm(const float* __restrict__ A0, const float* __restrict__ W0,
                           const float* __restrict__ A1, const float* __restrict__ W1,
                           const float* __restrict__ bias, int K, float* __restrict__ C,
                           const int* __restrict__ batch, float* __restrict__ psum) {
    __shared__ float As[16][68];   // [k][row], padded row-stride 68 (16B-aligned b128 reads)
    __shared__ float Bs[16][64];   // [k][col]
    int tid = threadIdx.x;
    int row0 = blockIdx.x * 64;
    int col0 = blockIdx.y * 64;
    int tr = (tid >> 4) * 4;
    int tc = (tid & 15) * 4;
    float acc[4][4] = {};

    for (int mat = 0; mat < 2; ++mat) {
        const float* A = mat ? A1 : A0;
        const float* W = mat ? W1 : W0;
        for (int k0 = 0; k0 < K; k0 += 16) {
            {   // A tile: thread loads float4 along K for one row, writes transposed
                int arow = tid >> 2;
                int kq = (tid & 3) * 4;
                float4 v = *(const float4*)(A + (size_t)(row0 + arow) * K + k0 + kq);
                As[kq + 0][arow] = v.x;
                As[kq + 1][arow] = v.y;
                As[kq + 2][arow] = v.z;
                As[kq + 3][arow] = v.w;
            }
            {   // B tile
                int krow = tid >> 4;
                int cq = (tid & 15) * 4;
                *(float4*)&Bs[krow][cq] = *(const float4*)(W + (size_t)(k0 + krow) * HID + col0 + cq);
            }
            __syncthreads();
#pragma unroll
            for (int kk = 0; kk < 16; ++kk) {
                float4 a = *(const float4*)&As[kk][tr];
                float4 b = *(const float4*)&Bs[kk][tc];
                acc[0][0] += a.x * b.x; acc[0][1] += a.x * b.y; acc[0][2] += a.x * b.z; acc[0][3] += a.x * b.w;
                acc[1][0] += a.y * b.x; acc[1][1] += a.y * b.y; acc[1][2] += a.y * b.z; acc[1][3] += a.y * b.w;
                acc[2][0] += a.z * b.x; acc[2][1] += a.z * b.y; acc[2][2] += a.z * b.z; acc[2][3] += a.z * b.w;
                acc[3][0] += a.w * b.x; acc[3][1] += a.w * b.y; acc[3][2] += a.w * b.z; acc[3][3] += a.w * b.w;
            }
            __syncthreads();
        }
    }

    float bv[4];
#pragma unroll
    for (int j = 0; j < 4; ++j) bv[j] = bias[col0 + tc + j];

    if constexpr (!POOL) {
#pragma unroll
        for (int i = 0; i < 4; ++i) {
            int r = row0 + tr + i;
            float4 v;
            v.x = fmaxf(acc[i][0] + bv[0], 0.f);
            v.y = fmaxf(acc[i][1] + bv[1], 0.f);
            v.z = fmaxf(acc[i][2] + bv[2], 0.f);
            v.w = fmaxf(acc[i][3] + bv[3], 0.f);
            *(float4*)(C + (size_t)r * HID + col0 + tc) = v;
        }
    } else {
        int b[4];
#pragma unroll
        for (int i = 0; i < 4; ++i) b[i] = batch[row0 + tr + i];
#pragma unroll
        for (int j = 0; j < 4; ++j) {
            int col = col0 + tc + j;
            float run = fmaxf(acc[0][j] + bv[j], 0.f);
            int cb = b[0];
#pragma unroll
            for (int i = 1; i < 4; ++i) {
                float v = fmaxf(acc[i][j] + bv[j], 0.f);
                if (b[i] == cb) {
                    run += v;
                } else {
                    atomicAdd(&psum[(size_t)cb * HID + col], run);
                    cb = b[i];
                    run = v;
                }
            }
            atomicAdd(&psum[(size_t)cb * HID + col], run);
        }
    }
}

// ---------------- pooling count + MLP head ----------------

__global__ void k_cnt(const int* __restrict__ batch, float* __restrict__ cnt) {
    int i = blockIdx.x * 256 + threadIdx.x;
    if (i < NNODES) atomicAdd(&cnt[batch[i]], 1.0f);
}

__global__ void k_head(const float* __restrict__ psum, const float* __restrict__ cnt,
                       const float* __restrict__ W1, const float* __restrict__ b1,
                       const float* __restrict__ W2, const float* __restrict__ b2,
                       const float* __restrict__ W3, const float* __restrict__ b3,
                       float* __restrict__ out) {
    __shared__ float pooled[HID];
    __shared__ float o1[64];
    __shared__ float o2[16];
    int g = blockIdx.x, t = threadIdx.x;
    float c = fmaxf(cnt[g], 1.0f);
    for (int k = t; k < HID; k += 64) pooled[k] = psum[(size_t)g * HID + k] / c;
    __syncthreads();
    float a = b1[t];
    for (int k = 0; k < HID; ++k) a += pooled[k] * W1[k * 64 + t];
    o1[t] = fmaxf(a, 0.f);
    __syncthreads();
    if (t < 16) {
        float a2 = b2[t];
        for (int k = 0; k < 64; ++k) a2 += o1[k] * W2[k * 16 + t];
        o2[t] = fmaxf(a2, 0.f);
    }
    __syncthreads();
    if (t == 0) {
        float a3 = b3[0];
        for (int k = 0; k < 16; ++k) a3 += o2[k] * W3[k];
        out[g] = a3;
    }
}

// ---------------- launch ----------------

extern "C" void kernel_launch(void* const* d_in, const int* in_sizes, int n_in,
                              void* d_out, int out_size, void* d_ws, size_t ws_size,
                              hipStream_t stream) {
    const float* x = (const float*)d_in[0];
    const int* ei = (const int*)d_in[1];
    const int* src = ei;
    const int* dst = ei + NEDGES;
    const float* ew = (const float*)d_in[2];
    const int* batch = (const int*)d_in[3];
    const float* Wr1 = (const float*)d_in[4];
    const float* br1 = (const float*)d_in[5];
    const float* Wo1 = (const float*)d_in[6];
    const float* Wr2 = (const float*)d_in[7];
    const float* br2 = (const float*)d_in[8];
    const float* Wo2 = (const float*)d_in[9];
    const float* W1 = (const float*)d_in[10];
    const float* b1 = (const float*)d_in[11];
    const float* W2 = (const float*)d_in[12];
    const float* b2 = (const float*)d_in[13];
    const float* W3 = (const float*)d_in[14];
    const float* b3 = (const float*)d_in[15];
    float* out = (float*)d_out;

    char* ws = (char*)d_ws;
    size_t o = 0;
    auto alloc = [&](size_t bytes) -> void* {
        void* p = ws + o;
        o = (o + bytes + 255) & ~(size_t)255;
        return p;
    };
    int* deg = (int*)alloc((size_t)NNODES * 4);
    int* off = (int*)alloc((size_t)(NNODES + 1) * 4);
    int* cur = (int*)alloc((size_t)NNODES * 4);
    int* csrc = (int*)alloc((size_t)NEDGES * 4);
    float* cw = (float*)alloc((size_t)NEDGES * 4);
    float* agg1 = (float*)alloc((size_t)NNODES * FIN * 4);
    float* h1 = (float*)alloc((size_t)NNODES * HID * 4);
    float* agg2 = (float*)alloc((size_t)NNODES * HID * 4);
    float* psum = (float*)alloc((size_t)NGRAPH * HID * 4);
    float* cnt = (float*)alloc((size_t)NGRAPH * 4);

    hipMemsetAsync(deg, 0, (size_t)NNODES * 4, stream);
    hipMemsetAsync(psum, 0, (size_t)NGRAPH * HID * 4, stream);
    hipMemsetAsync(cnt, 0, (size_t)NGRAPH * 4, stream);

    k_deg<<<(NEDGES + 255) / 256, 256, 0, stream>>>(dst, deg);
    k_scan<<<1, 1024, 0, stream>>>(deg, off, cur);
    k_fill<<<(NEDGES + 255) / 256, 256, 0, stream>>>(src, dst, ew, cur, csrc, cw);

    k_agg128<<<(NNODES + 3) / 4, 256, 0, stream>>>(x, off, csrc, cw, agg1);

    dim3 gg(NNODES / 64, HID / 64);
    k_dualgemm<false><<<gg, 256, 0, stream>>>(agg1, Wr1, x, Wo1, br1, FIN, h1, nullptr, nullptr);

    k_agg512<<<(NNODES + 3) / 4, 256, 0, stream>>>(h1, off, csrc, cw, agg2);
    k_cnt<<<(NNODES + 255) / 256, 256, 0, stream>>>(batch, cnt);

    k_dualgemm<true><<<gg, 256, 0, stream>>>(agg2, Wr2, h1, Wo2, br2, HID, nullptr, batch, psum);

    k_head<<<NGRAPH, 64, 0, stream>>>(psum, cnt, W1, b1, W2, b2, W3, b3, out);
}

// Round 2
// 770.340 us; speedup vs baseline: 1.8278x; 1.8278x over previous
//
#include <hip/hip_runtime.h>
#include <hip/hip_bf16.h>

#define NNODES 40000
#define MPAD   40064   // 313 * 128
#define NEDGES 640000
#define FIN    128
#define HID    512
#define NGRAPH 64

typedef __attribute__((ext_vector_type(8))) short bf16x8;
typedef __attribute__((ext_vector_type(4))) float f32x4;

__device__ __forceinline__ unsigned short f2bf(float f) {
    unsigned int u = __builtin_bit_cast(unsigned int, f);
    u += 0x7FFFu + ((u >> 16) & 1u);   // RNE
    return (unsigned short)(u >> 16);
}
__device__ __forceinline__ float bf2f(unsigned short s) {
    return __builtin_bit_cast(float, (unsigned int)s << 16);
}

__device__ __forceinline__ void gload_lds16(const void* g, void* l) {
    __builtin_amdgcn_global_load_lds(
        (const __attribute__((address_space(1))) void*)g,
        (__attribute__((address_space(3))) void*)l, 16, 0, 0);
}

// ---------------- conversions ----------------

// x [NNODES][128] f32 -> xb [MPAD][128] bf16 (pad rows zero)
__global__ void k_cvt_x(const float* __restrict__ x, unsigned short* __restrict__ xb) {
    size_t e = ((size_t)blockIdx.x * 256 + threadIdx.x) * 8;
    if (e >= (size_t)MPAD * FIN) return;
    bf16x8 o;
    if (e < (size_t)NNODES * FIN) {
        float4 v0 = *(const float4*)(x + e);
        float4 v1 = *(const float4*)(x + e + 4);
        o[0] = f2bf(v0.x); o[1] = f2bf(v0.y); o[2] = f2bf(v0.z); o[3] = f2bf(v0.w);
        o[4] = f2bf(v1.x); o[5] = f2bf(v1.y); o[6] = f2bf(v1.z); o[7] = f2bf(v1.w);
    } else {
        o = (bf16x8)0;
    }
    *(bf16x8*)(xb + e) = o;
}

// W [K][512] f32 -> Wt [512][K] bf16 (transpose + convert)
__global__ void k_cvt_wt(const float* __restrict__ W, unsigned short* __restrict__ Wt, int K) {
    int t = blockIdx.x * 256 + threadIdx.x;
    if (t >= 512 * K) return;
    int n = t / K, k = t - n * K;
    Wt[t] = f2bf(W[(size_t)k * 512 + n]);
}

// ---------------- CSR build ----------------

__global__ void k_deg(const int* __restrict__ dst, int* __restrict__ deg) {
    int e = blockIdx.x * 256 + threadIdx.x;
    if (e < NEDGES) atomicAdd(&deg[dst[e]], 1);
}

__global__ void k_scan(const int* __restrict__ deg, int* __restrict__ off, int* __restrict__ cursor) {
    __shared__ int sh[1024];
    constexpr int CH = (NNODES + 1023) / 1024;
    int t = threadIdx.x;
    int base = t * CH;
    int vals[CH];
    int local = 0;
#pragma unroll
    for (int i = 0; i < CH; ++i) {
        int idx = base + i;
        int v = (idx < NNODES) ? deg[idx] : 0;
        vals[i] = v;
        local += v;
    }
    sh[t] = local;
    __syncthreads();
    for (int o = 1; o < 1024; o <<= 1) {
        int add = (t >= o) ? sh[t - o] : 0;
        __syncthreads();
        sh[t] += add;
        __syncthreads();
    }
    int run = sh[t] - local;
#pragma unroll
    for (int i = 0; i < CH; ++i) {
        int idx = base + i;
        if (idx < NNODES) {
            off[idx] = run;
            cursor[idx] = run;
            run += vals[i];
        }
    }
    if (t == 1023) off[NNODES] = sh[1023];
}

__global__ void k_fill(const int* __restrict__ src, const int* __restrict__ dst,
                       const float* __restrict__ ew, int* __restrict__ cursor,
                       int* __restrict__ csrc, float* __restrict__ cw) {
    int e = blockIdx.x * 256 + threadIdx.x;
    if (e < NEDGES) {
        int p = atomicAdd(&cursor[dst[e]], 1);
        csrc[p] = src[e];
        cw[p] = ew[e];
    }
}

// ---------------- aggregation (gather, bf16 in/out, fp32 accum) ----------------

__global__ void k_agg128(const unsigned short* __restrict__ xb, const int* __restrict__ off,
                         const int* __restrict__ csrc, const float* __restrict__ cw,
                         unsigned short* __restrict__ out) {
    int node = blockIdx.x * 4 + (threadIdx.x >> 6);
    if (node >= NNODES) return;
    int lane = threadIdx.x & 63;
    float a0 = 0.f, a1 = 0.f;
    int s = off[node], e = off[node + 1];
    for (int k = s; k < e; ++k) {
        int j = csrc[k];
        float w = cw[k];
        unsigned int v = *(const unsigned int*)(xb + (size_t)j * FIN + lane * 2);
        a0 += w * bf2f((unsigned short)(v & 0xFFFF));
        a1 += w * bf2f((unsigned short)(v >> 16));
    }
    unsigned int o = (unsigned int)f2bf(a0) | ((unsigned int)f2bf(a1) << 16);
    *(unsigned int*)(out + (size_t)node * FIN + lane * 2) = o;
}

__global__ void k_agg512(const unsigned short* __restrict__ h, const int* __restrict__ off,
                         const int* __restrict__ csrc, const float* __restrict__ cw,
                         unsigned short* __restrict__ out) {
    int node = blockIdx.x * 4 + (threadIdx.x >> 6);
    if (node >= NNODES) return;
    int lane = threadIdx.x & 63;
    float acc[8] = {};
    int s = off[node], e = off[node + 1];
    for (int k = s; k < e; ++k) {
        int j = csrc[k];
        float w = cw[k];
        bf16x8 a = *(const bf16x8*)(h + (size_t)j * HID + lane * 8);
#pragma unroll
        for (int q = 0; q < 8; ++q)
            acc[q] += w * bf2f((unsigned short)a[q]);
    }
    bf16x8 o;
#pragma unroll
    for (int q = 0; q < 8; ++q) o[q] = (short)f2bf(acc[q]);
    *(bf16x8*)(out + (size_t)node * HID + lane * 8) = o;
}

// ---------------- dual MFMA GEMM: C = relu(A0@B0 + A1@B1 + bias) ----------------
// A: [MPAD][K] bf16 row-major; Bt: [512][K] bf16 (pre-transposed weights).
// 128x128 tile, BK=32, 4 waves (2x2 of 64x64), 4x4 16x16x32 fragments per wave.
// POOL: relu'd rows merged by batch id and atomicAdd'ed into psum[64][512].

template <bool POOL>
__global__ __launch_bounds__(256)
void k_mfma_dual(const unsigned short* __restrict__ A0, const unsigned short* __restrict__ B0t,
                 const unsigned short* __restrict__ A1, const unsigned short* __restrict__ B1t,
                 const float* __restrict__ bias, int K,
                 unsigned short* __restrict__ C,
                 const int* __restrict__ batch, float* __restrict__ psum) {
    __shared__ unsigned short As[128 * 32];
    __shared__ unsigned short Bs[128 * 32];
    int tid = threadIdx.x;
    int l = tid & 63, w = tid >> 6;
    int wr = w >> 1, wc = w & 1;
    int row0 = blockIdx.x * 128;
    int col0 = blockIdx.y * 128;
    int lr = l & 15, lk = (l >> 4) * 8;

    f32x4 acc[4][4];
#pragma unroll
    for (int m = 0; m < 4; ++m)
#pragma unroll
        for (int n = 0; n < 4; ++n) acc[m][n] = (f32x4)0.f;

#pragma unroll
    for (int mat = 0; mat < 2; ++mat) {
        const unsigned short* A = mat ? A1 : A0;
        const unsigned short* Bt = mat ? B1t : B0t;
        for (int k0 = 0; k0 < K; k0 += 32) {
            // stage 128x32 of A and 128x32 of Bt, linear LDS, 16B per lane
#pragma unroll
            for (int i = 0; i < 2; ++i) {
                int c = tid + i * 256;             // chunk id, 8 bf16 each
                int r = c >> 2, kk = (c & 3) * 8;
                gload_lds16(A + (size_t)(row0 + r) * K + k0 + kk, &As[c * 8]);
                gload_lds16(Bt + (size_t)(col0 + r) * K + k0 + kk, &Bs[c * 8]);
            }
            __syncthreads();
            bf16x8 af[4], bf[4];
#pragma unroll
            for (int m = 0; m < 4; ++m)
                af[m] = *(const bf16x8*)&As[(wr * 64 + m * 16 + lr) * 32 + lk];
#pragma unroll
            for (int n = 0; n < 4; ++n)
                bf[n] = *(const bf16x8*)&Bs[(wc * 64 + n * 16 + lr) * 32 + lk];
#pragma unroll
            for (int m = 0; m < 4; ++m)
#pragma unroll
                for (int n = 0; n < 4; ++n)
                    acc[m][n] = __builtin_amdgcn_mfma_f32_16x16x32_bf16(af[m], bf[n], acc[m][n], 0, 0, 0);
            __syncthreads();
        }
    }

    // epilogue: C/D layout col = l&15, row = (l>>4)*4 + i
    float bv[4];
#pragma unroll
    for (int n = 0; n < 4; ++n) bv[n] = bias[col0 + wc * 64 + n * 16 + lr];
    int rbase = row0 + wr * 64 + (l >> 4) * 4;

    if constexpr (!POOL) {
#pragma unroll
        for (int m = 0; m < 4; ++m) {
#pragma unroll
            for (int i = 0; i < 4; ++i) {
                int r = rbase + m * 16 + i;
                if (r < NNODES) {
#pragma unroll
                    for (int n = 0; n < 4; ++n) {
                        int col = col0 + wc * 64 + n * 16 + lr;
                        C[(size_t)r * HID + col] = f2bf(fmaxf(acc[m][n][i] + bv[n], 0.f));
                    }
                }
            }
        }
    } else {
#pragma unroll
        for (int m = 0; m < 4; ++m) {
            int b[4];
#pragma unroll
            for (int i = 0; i < 4; ++i) {
                int r = rbase + m * 16 + i;
                b[i] = (r < NNODES) ? batch[r] : -1;
            }
#pragma unroll
            for (int n = 0; n < 4; ++n) {
                int col = col0 + wc * 64 + n * 16 + lr;
                int cb = -1;
                float run = 0.f;
#pragma unroll
                for (int i = 0; i < 4; ++i) {
                    if (b[i] >= 0) {
                        float v = fmaxf(acc[m][n][i] + bv[n], 0.f);
                        if (b[i] == cb) {
                            run += v;
                        } else {
                            if (cb >= 0) atomicAdd(&psum[(size_t)cb * HID + col], run);
                            cb = b[i];
                            run = v;
                        }
                    }
                }
                if (cb >= 0) atomicAdd(&psum[(size_t)cb * HID + col], run);
            }
        }
    }
}

// ---------------- pooling count + MLP head (fp32) ----------------

__global__ void k_cnt(const int* __restrict__ batch, float* __restrict__ cnt) {
    int i = blockIdx.x * 256 + threadIdx.x;
    if (i < NNODES) atomicAdd(&cnt[batch[i]], 1.0f);
}

__global__ void k_head(const float* __restrict__ psum, const float* __restrict__ cnt,
                       const float* __restrict__ W1, const float* __restrict__ b1,
                       const float* __restrict__ W2, const float* __restrict__ b2,
                       const float* __restrict__ W3, const float* __restrict__ b3,
                       float* __restrict__ out) {
    __shared__ float pooled[HID];
    __shared__ float o1[64];
    __shared__ float o2[16];
    int g = blockIdx.x, t = threadIdx.x;
    float c = fmaxf(cnt[g], 1.0f);
    for (int k = t; k < HID; k += 64) pooled[k] = psum[(size_t)g * HID + k] / c;
    __syncthreads();
    float a = b1[t];
    for (int k = 0; k < HID; ++k) a += pooled[k] * W1[k * 64 + t];
    o1[t] = fmaxf(a, 0.f);
    __syncthreads();
    if (t < 16) {
        float a2 = b2[t];
        for (int k = 0; k < 64; ++k) a2 += o1[k] * W2[k * 16 + t];
        o2[t] = fmaxf(a2, 0.f);
    }
    __syncthreads();
    if (t == 0) {
        float a3 = b3[0];
        for (int k = 0; k < 16; ++k) a3 += o2[k] * W3[k];
        out[g] = a3;
    }
}

// ---------------- launch ----------------

extern "C" void kernel_launch(void* const* d_in, const int* in_sizes, int n_in,
                              void* d_out, int out_size, void* d_ws, size_t ws_size,
                              hipStream_t stream) {
    const float* x = (const float*)d_in[0];
    const int* ei = (const int*)d_in[1];
    const int* src = ei;
    const int* dst = ei + NEDGES;
    const float* ew = (const float*)d_in[2];
    const int* batch = (const int*)d_in[3];
    const float* Wr1 = (const float*)d_in[4];
    const float* br1 = (const float*)d_in[5];
    const float* Wo1 = (const float*)d_in[6];
    const float* Wr2 = (const float*)d_in[7];
    const float* br2 = (const float*)d_in[8];
    const float* Wo2 = (const float*)d_in[9];
    const float* W1 = (const float*)d_in[10];
    const float* b1 = (const float*)d_in[11];
    const float* W2 = (const float*)d_in[12];
    const float* b2 = (const float*)d_in[13];
    const float* W3 = (const float*)d_in[14];
    const float* b3 = (const float*)d_in[15];
    float* out = (float*)d_out;

    char* ws = (char*)d_ws;
    size_t o = 0;
    auto alloc = [&](size_t bytes) -> void* {
        void* p = ws + o;
        o = (o + bytes + 255) & ~(size_t)255;
        return p;
    };
    int* deg = (int*)alloc((size_t)NNODES * 4);
    int* off = (int*)alloc((size_t)(NNODES + 1) * 4);
    int* cur = (int*)alloc((size_t)NNODES * 4);
    int* csrc = (int*)alloc((size_t)NEDGES * 4);
    float* cw = (float*)alloc((size_t)NEDGES * 4);
    unsigned short* xb = (unsigned short*)alloc((size_t)MPAD * FIN * 2);
    unsigned short* agg1 = (unsigned short*)alloc((size_t)MPAD * FIN * 2);
    unsigned short* h1 = (unsigned short*)alloc((size_t)MPAD * HID * 2);
    unsigned short* agg2 = (unsigned short*)alloc((size_t)MPAD * HID * 2);
    unsigned short* Wr1t = (unsigned short*)alloc((size_t)512 * FIN * 2);
    unsigned short* Wo1t = (unsigned short*)alloc((size_t)512 * FIN * 2);
    unsigned short* Wr2t = (unsigned short*)alloc((size_t)512 * HID * 2);
    unsigned short* Wo2t = (unsigned short*)alloc((size_t)512 * HID * 2);
    float* psum = (float*)alloc((size_t)NGRAPH * HID * 4);
    float* cnt = (float*)alloc((size_t)NGRAPH * 4);

    hipMemsetAsync(deg, 0, (size_t)NNODES * 4, stream);
    hipMemsetAsync(psum, 0, (size_t)NGRAPH * HID * 4, stream);
    hipMemsetAsync(cnt, 0, (size_t)NGRAPH * 4, stream);

    // conversions
    k_cvt_x<<<(MPAD * FIN / 8 + 255) / 256, 256, 0, stream>>>(x, xb);
    k_cvt_wt<<<(512 * FIN + 255) / 256, 256, 0, stream>>>(Wr1, Wr1t, FIN);
    k_cvt_wt<<<(512 * FIN + 255) / 256, 256, 0, stream>>>(Wo1, Wo1t, FIN);
    k_cvt_wt<<<(512 * HID + 255) / 256, 256, 0, stream>>>(Wr2, Wr2t, HID);
    k_cvt_wt<<<(512 * HID + 255) / 256, 256, 0, stream>>>(Wo2, Wo2t, HID);

    // CSR
    k_deg<<<(NEDGES + 255) / 256, 256, 0, stream>>>(dst, deg);
    k_scan<<<1, 1024, 0, stream>>>(deg, off, cur);
    k_fill<<<(NEDGES + 255) / 256, 256, 0, stream>>>(src, dst, ew, cur, csrc, cw);

    // layer 1
    k_agg128<<<(NNODES + 3) / 4, 256, 0, stream>>>(xb, off, csrc, cw, agg1);
    dim3 gg(MPAD / 128, HID / 128);
    k_mfma_dual<false><<<gg, 256, 0, stream>>>(agg1, Wr1t, xb, Wo1t, br1, FIN, h1, nullptr, nullptr);

    // layer 2 (+ fused mean-pool numerator)
    k_agg512<<<(NNODES + 3) / 4, 256, 0, stream>>>(h1, off, csrc, cw, agg2);
    k_cnt<<<(NNODES + 255) / 256, 256, 0, stream>>>(batch, cnt);
    k_mfma_dual<true><<<gg, 256, 0, stream>>>(agg2, Wr2t, h1, Wo2t, br2, HID, nullptr, batch, psum);

    // head
    k_head<<<NGRAPH, 64, 0, stream>>>(psum, cnt, W1, b1, W2, b2, W3, b3, out);
}

// Round 3
// 531.380 us; speedup vs baseline: 2.6498x; 1.4497x over previous
//
#include <hip/hip_runtime.h>
#include <hip/hip_bf16.h>

#define NNODES 40000
#define MPAD   40064   // 313 * 128
#define NEDGES 640000
#define FIN    128
#define HID    512
#define NGRAPH 64

typedef __attribute__((ext_vector_type(8))) short bf16x8;
typedef __attribute__((ext_vector_type(4))) float f32x4;

__device__ __forceinline__ unsigned short f2bf(float f) {
    unsigned int u = __builtin_bit_cast(unsigned int, f);
    u += 0x7FFFu + ((u >> 16) & 1u);   // RNE
    return (unsigned short)(u >> 16);
}
__device__ __forceinline__ float bf2f(unsigned short s) {
    return __builtin_bit_cast(float, (unsigned int)s << 16);
}

__device__ __forceinline__ void gload_lds16(const void* g, void* l) {
    __builtin_amdgcn_global_load_lds(
        (const __attribute__((address_space(1))) void*)g,
        (__attribute__((address_space(3))) void*)l, 16, 0, 0);
}

// ---------------- conversions ----------------

// x [NNODES][128] f32 -> xb [MPAD][128] bf16 (pad rows zero)
__global__ void k_cvt_x(const float* __restrict__ x, unsigned short* __restrict__ xb) {
    size_t e = ((size_t)blockIdx.x * 256 + threadIdx.x) * 8;
    if (e >= (size_t)MPAD * FIN) return;
    bf16x8 o;
    if (e < (size_t)NNODES * FIN) {
        float4 v0 = *(const float4*)(x + e);
        float4 v1 = *(const float4*)(x + e + 4);
        o[0] = f2bf(v0.x); o[1] = f2bf(v0.y); o[2] = f2bf(v0.z); o[3] = f2bf(v0.w);
        o[4] = f2bf(v1.x); o[5] = f2bf(v1.y); o[6] = f2bf(v1.z); o[7] = f2bf(v1.w);
    } else {
        o = (bf16x8)0;
    }
    *(bf16x8*)(xb + e) = o;
}

// W [K][512] f32 -> Wt [512][K] bf16 (transpose + convert)
__global__ void k_cvt_wt(const float* __restrict__ W, unsigned short* __restrict__ Wt, int K) {
    int t = blockIdx.x * 256 + threadIdx.x;
    if (t >= 512 * K) return;
    int n = t / K, k = t - n * K;
    Wt[t] = f2bf(W[(size_t)k * 512 + n]);
}

// ---------------- CSR build ----------------

__global__ void k_deg(const int* __restrict__ dst, int* __restrict__ deg) {
    int e = blockIdx.x * 256 + threadIdx.x;
    if (e < NEDGES) atomicAdd(&deg[dst[e]], 1);
}

__global__ void k_scan(const int* __restrict__ deg, int* __restrict__ off, int* __restrict__ cursor) {
    __shared__ int sh[1024];
    constexpr int CH = (NNODES + 1023) / 1024;
    int t = threadIdx.x;
    int base = t * CH;
    int vals[CH];
    int local = 0;
#pragma unroll
    for (int i = 0; i < CH; ++i) {
        int idx = base + i;
        int v = (idx < NNODES) ? deg[idx] : 0;
        vals[i] = v;
        local += v;
    }
    sh[t] = local;
    __syncthreads();
    for (int o = 1; o < 1024; o <<= 1) {
        int add = (t >= o) ? sh[t - o] : 0;
        __syncthreads();
        sh[t] += add;
        __syncthreads();
    }
    int run = sh[t] - local;
#pragma unroll
    for (int i = 0; i < CH; ++i) {
        int idx = base + i;
        if (idx < NNODES) {
            off[idx] = run;
            cursor[idx] = run;
            run += vals[i];
        }
    }
    if (t == 1023) off[NNODES] = sh[1023];
}

__global__ void k_fill(const int* __restrict__ src, const int* __restrict__ dst,
                       const float* __restrict__ ew, int* __restrict__ cursor,
                       int* __restrict__ csrc, float* __restrict__ cw) {
    int e = blockIdx.x * 256 + threadIdx.x;
    if (e < NEDGES) {
        int p = atomicAdd(&cursor[dst[e]], 1);
        csrc[p] = src[e];
        cw[p] = ew[e];
    }
}

// ---------------- aggregation (gather, bf16 in/out, fp32 accum) ----------------

__global__ void k_agg128(const unsigned short* __restrict__ xb, const int* __restrict__ off,
                         const int* __restrict__ csrc, const float* __restrict__ cw,
                         unsigned short* __restrict__ out) {
    int node = blockIdx.x * 4 + (threadIdx.x >> 6);
    if (node >= NNODES) return;
    int lane = threadIdx.x & 63;
    float a0 = 0.f, a1 = 0.f;
    int s = off[node], e = off[node + 1];
    for (int k = s; k < e; ++k) {
        int j = csrc[k];
        float w = cw[k];
        unsigned int v = *(const unsigned int*)(xb + (size_t)j * FIN + lane * 2);
        a0 += w * bf2f((unsigned short)(v & 0xFFFF));
        a1 += w * bf2f((unsigned short)(v >> 16));
    }
    unsigned int o = (unsigned int)f2bf(a0) | ((unsigned int)f2bf(a1) << 16);
    *(unsigned int*)(out + (size_t)node * FIN + lane * 2) = o;
}

__global__ void k_agg512(const unsigned short* __restrict__ h, const int* __restrict__ off,
                         const int* __restrict__ csrc, const float* __restrict__ cw,
                         unsigned short* __restrict__ out) {
    int node = blockIdx.x * 4 + (threadIdx.x >> 6);
    if (node >= NNODES) return;
    int lane = threadIdx.x & 63;
    float acc[8] = {};
    int s = off[node], e = off[node + 1];
    for (int k = s; k < e; ++k) {
        int j = csrc[k];
        float w = cw[k];
        bf16x8 a = *(const bf16x8*)(h + (size_t)j * HID + lane * 8);
#pragma unroll
        for (int q = 0; q < 8; ++q)
            acc[q] += w * bf2f((unsigned short)a[q]);
    }
    bf16x8 o;
#pragma unroll
    for (int q = 0; q < 8; ++q) o[q] = (short)f2bf(acc[q]);
    *(bf16x8*)(out + (size_t)node * HID + lane * 8) = o;
}

// ---------------- dual MFMA GEMM: C = relu(A0@B0 + A1@B1 + bias) ----------------
// A: [MPAD][K] bf16 row-major; Bt: [512][K] bf16 (pre-transposed weights).
// 128x128 tile, BK=32, 4 waves (2x2 of 64x64), 4x4 16x16x32 fragments per wave.
// POOL: relu'd rows merged by batch id and atomicAdd'ed into psum[64][512].

template <bool POOL>
__global__ __launch_bounds__(256)
void k_mfma_dual(const unsigned short* __restrict__ A0, const unsigned short* __restrict__ B0t,
                 const unsigned short* __restrict__ A1, const unsigned short* __restrict__ B1t,
                 const float* __restrict__ bias, int K,
                 unsigned short* __restrict__ C,
                 const int* __restrict__ batch, float* __restrict__ psum) {
    __shared__ unsigned short As[128 * 32];
    __shared__ unsigned short Bs[128 * 32];
    int tid = threadIdx.x;
    int l = tid & 63, w = tid >> 6;
    int wr = w >> 1, wc = w & 1;
    int row0 = blockIdx.x * 128;
    int col0 = blockIdx.y * 128;
    int lr = l & 15, lk = (l >> 4) * 8;

    f32x4 acc[4][4];
#pragma unroll
    for (int m = 0; m < 4; ++m)
#pragma unroll
        for (int n = 0; n < 4; ++n) acc[m][n] = (f32x4)0.f;

#pragma unroll
    for (int mat = 0; mat < 2; ++mat) {
        const unsigned short* A = mat ? A1 : A0;
        const unsigned short* Bt = mat ? B1t : B0t;
        for (int k0 = 0; k0 < K; k0 += 32) {
            // stage 128x32 of A and 128x32 of Bt, linear LDS, 16B per lane
#pragma unroll
            for (int i = 0; i < 2; ++i) {
                int c = tid + i * 256;             // chunk id, 8 bf16 each
                int r = c >> 2, kk = (c & 3) * 8;
                gload_lds16(A + (size_t)(row0 + r) * K + k0 + kk, &As[c * 8]);
                gload_lds16(Bt + (size_t)(col0 + r) * K + k0 + kk, &Bs[c * 8]);
            }
            __syncthreads();
            bf16x8 af[4], bf[4];
#pragma unroll
            for (int m = 0; m < 4; ++m)
                af[m] = *(const bf16x8*)&As[(wr * 64 + m * 16 + lr) * 32 + lk];
#pragma unroll
            for (int n = 0; n < 4; ++n)
                bf[n] = *(const bf16x8*)&Bs[(wc * 64 + n * 16 + lr) * 32 + lk];
#pragma unroll
            for (int m = 0; m < 4; ++m)
#pragma unroll
                for (int n = 0; n < 4; ++n)
                    acc[m][n] = __builtin_amdgcn_mfma_f32_16x16x32_bf16(af[m], bf[n], acc[m][n], 0, 0, 0);
            __syncthreads();
        }
    }

    // epilogue: C/D layout col = l&15, row = (l>>4)*4 + i
    float bv[4];
#pragma unroll
    for (int n = 0; n < 4; ++n) bv[n] = bias[col0 + wc * 64 + n * 16 + lr];
    int rbase = row0 + wr * 64 + (l >> 4) * 4;

    if constexpr (!POOL) {
#pragma unroll
        for (int m = 0; m < 4; ++m) {
#pragma unroll
            for (int i = 0; i < 4; ++i) {
                int r = rbase + m * 16 + i;
                if (r < NNODES) {
#pragma unroll
                    for (int n = 0; n < 4; ++n) {
                        int col = col0 + wc * 64 + n * 16 + lr;
                        C[(size_t)r * HID + col] = f2bf(fmaxf(acc[m][n][i] + bv[n], 0.f));
                    }
                }
            }
        }
    } else {
#pragma unroll
        for (int m = 0; m < 4; ++m) {
            int b[4];
#pragma unroll
            for (int i = 0; i < 4; ++i) {
                int r = rbase + m * 16 + i;
                b[i] = (r < NNODES) ? batch[r] : -1;
            }
#pragma unroll
            for (int n = 0; n < 4; ++n) {
                int col = col0 + wc * 64 + n * 16 + lr;
                int cb = -1;
                float run = 0.f;
#pragma unroll
                for (int i = 0; i < 4; ++i) {
                    if (b[i] >= 0) {
                        float v = fmaxf(acc[m][n][i] + bv[n], 0.f);
                        if (b[i] == cb) {
                            run += v;
                        } else {
                            if (cb >= 0) atomicAdd(&psum[(size_t)cb * HID + col], run);
                            cb = b[i];
                            run = v;
                        }
                    }
                }
                if (cb >= 0) atomicAdd(&psum[(size_t)cb * HID + col], run);
            }
        }
    }
}

// ---------------- pooling count (LDS histogram) + MLP head (fp32) ----------------

__global__ void k_cnt(const int* __restrict__ batch, float* __restrict__ cnt) {
    __shared__ int h[NGRAPH];
    int t = threadIdx.x;
    if (t < NGRAPH) h[t] = 0;
    __syncthreads();
    int i = blockIdx.x * 256 + t;
    if (i < NNODES) atomicAdd(&h[batch[i]], 1);
    __syncthreads();
    if (t < NGRAPH && h[t] != 0) atomicAdd(&cnt[t], (float)h[t]);
}

__global__ void k_head(const float* __restrict__ psum, const float* __restrict__ cnt,
                       const float* __restrict__ W1, const float* __restrict__ b1,
                       const float* __restrict__ W2, const float* __restrict__ b2,
                       const float* __restrict__ W3, const float* __restrict__ b3,
                       float* __restrict__ out) {
    __shared__ float pooled[HID];
    __shared__ float o1[64];
    __shared__ float o2[16];
    int g = blockIdx.x, t = threadIdx.x;
    float c = fmaxf(cnt[g], 1.0f);
    for (int k = t; k < HID; k += 64) pooled[k] = psum[(size_t)g * HID + k] / c;
    __syncthreads();
    float a = b1[t];
    for (int k = 0; k < HID; ++k) a += pooled[k] * W1[k * 64 + t];
    o1[t] = fmaxf(a, 0.f);
    __syncthreads();
    if (t < 16) {
        float a2 = b2[t];
        for (int k = 0; k < 64; ++k) a2 += o1[k] * W2[k * 16 + t];
        o2[t] = fmaxf(a2, 0.f);
    }
    __syncthreads();
    if (t == 0) {
        float a3 = b3[0];
        for (int k = 0; k < 16; ++k) a3 += o2[k] * W3[k];
        out[g] = a3;
    }
}

// ---------------- launch ----------------

extern "C" void kernel_launch(void* const* d_in, const int* in_sizes, int n_in,
                              void* d_out, int out_size, void* d_ws, size_t ws_size,
                              hipStream_t stream) {
    const float* x = (const float*)d_in[0];
    const int* ei = (const int*)d_in[1];
    const int* src = ei;
    const int* dst = ei + NEDGES;
    const float* ew = (const float*)d_in[2];
    const int* batch = (const int*)d_in[3];
    const float* Wr1 = (const float*)d_in[4];
    const float* br1 = (const float*)d_in[5];
    const float* Wo1 = (const float*)d_in[6];
    const float* Wr2 = (const float*)d_in[7];
    const float* br2 = (const float*)d_in[8];
    const float* Wo2 = (const float*)d_in[9];
    const float* W1 = (const float*)d_in[10];
    const float* b1 = (const float*)d_in[11];
    const float* W2 = (const float*)d_in[12];
    const float* b2 = (const float*)d_in[13];
    const float* W3 = (const float*)d_in[14];
    const float* b3 = (const float*)d_in[15];
    float* out = (float*)d_out;

    char* ws = (char*)d_ws;
    size_t o = 0;
    auto alloc = [&](size_t bytes) -> void* {
        void* p = ws + o;
        o = (o + bytes + 255) & ~(size_t)255;
        return p;
    };
    int* deg = (int*)alloc((size_t)NNODES * 4);
    int* off = (int*)alloc((size_t)(NNODES + 1) * 4);
    int* cur = (int*)alloc((size_t)NNODES * 4);
    int* csrc = (int*)alloc((size_t)NEDGES * 4);
    float* cw = (float*)alloc((size_t)NEDGES * 4);
    unsigned short* xb = (unsigned short*)alloc((size_t)MPAD * FIN * 2);
    unsigned short* agg1 = (unsigned short*)alloc((size_t)MPAD * FIN * 2);
    unsigned short* h1 = (unsigned short*)alloc((size_t)MPAD * HID * 2);
    unsigned short* agg2 = (unsigned short*)alloc((size_t)MPAD * HID * 2);
    unsigned short* Wr1t = (unsigned short*)alloc((size_t)512 * FIN * 2);
    unsigned short* Wo1t = (unsigned short*)alloc((size_t)512 * FIN * 2);
    unsigned short* Wr2t = (unsigned short*)alloc((size_t)512 * HID * 2);
    unsigned short* Wo2t = (unsigned short*)alloc((size_t)512 * HID * 2);
    float* psum = (float*)alloc((size_t)NGRAPH * HID * 4);
    float* cnt = (float*)alloc((size_t)NGRAPH * 4);

    hipMemsetAsync(deg, 0, (size_t)NNODES * 4, stream);
    hipMemsetAsync(psum, 0, (size_t)NGRAPH * HID * 4, stream);
    hipMemsetAsync(cnt, 0, (size_t)NGRAPH * 4, stream);

    // conversions
    k_cvt_x<<<(MPAD * FIN / 8 + 255) / 256, 256, 0, stream>>>(x, xb);
    k_cvt_wt<<<(512 * FIN + 255) / 256, 256, 0, stream>>>(Wr1, Wr1t, FIN);
    k_cvt_wt<<<(512 * FIN + 255) / 256, 256, 0, stream>>>(Wo1, Wo1t, FIN);
    k_cvt_wt<<<(512 * HID + 255) / 256, 256, 0, stream>>>(Wr2, Wr2t, HID);
    k_cvt_wt<<<(512 * HID + 255) / 256, 256, 0, stream>>>(Wo2, Wo2t, HID);

    // CSR
    k_deg<<<(NEDGES + 255) / 256, 256, 0, stream>>>(dst, deg);
    k_scan<<<1, 1024, 0, stream>>>(deg, off, cur);
    k_fill<<<(NEDGES + 255) / 256, 256, 0, stream>>>(src, dst, ew, cur, csrc, cw);

    // layer 1
    k_agg128<<<(NNODES + 3) / 4, 256, 0, stream>>>(xb, off, csrc, cw, agg1);
    dim3 gg(MPAD / 128, HID / 128);
    k_mfma_dual<false><<<gg, 256, 0, stream>>>(agg1, Wr1t, xb, Wo1t, br1, FIN, h1, nullptr, nullptr);

    // layer 2 (+ fused mean-pool numerator)
    k_agg512<<<(NNODES + 3) / 4, 256, 0, stream>>>(h1, off, csrc, cw, agg2);
    k_cnt<<<(NNODES + 255) / 256, 256, 0, stream>>>(batch, cnt);
    k_mfma_dual<true><<<gg, 256, 0, stream>>>(agg2, Wr2t, h1, Wo2t, br2, HID, nullptr, batch, psum);

    // head
    k_head<<<NGRAPH, 64, 0, stream>>>(psum, cnt, W1, b1, W2, b2, W3, b3, out);
}

// Round 4
// 484.688 us; speedup vs baseline: 2.9051x; 1.0963x over previous
//
#include <hip/hip_runtime.h>
#include <hip/hip_bf16.h>

#define NNODES 40000
#define MPAD   40064   // 313 * 128
#define NEDGES 640000
#define FIN    128
#define HID    512
#define NGRAPH 64

typedef __attribute__((ext_vector_type(8))) short bf16x8;
typedef __attribute__((ext_vector_type(4))) float f32x4;

__device__ __forceinline__ unsigned short f2bf(float f) {
    unsigned int u = __builtin_bit_cast(unsigned int, f);
    u += 0x7FFFu + ((u >> 16) & 1u);   // RNE
    return (unsigned short)(u >> 16);
}
__device__ __forceinline__ float bf2f(unsigned short s) {
    return __builtin_bit_cast(float, (unsigned int)s << 16);
}

__device__ __forceinline__ void gload_lds16(const void* g, void* l) {
    __builtin_amdgcn_global_load_lds(
        (const __attribute__((address_space(1))) void*)g,
        (__attribute__((address_space(3))) void*)l, 16, 0, 0);
}

// ---------------- conversions ----------------

__global__ void k_cvt_x(const float* __restrict__ x, unsigned short* __restrict__ xb) {
    size_t e = ((size_t)blockIdx.x * 256 + threadIdx.x) * 8;
    if (e >= (size_t)MPAD * FIN) return;
    bf16x8 o;
    if (e < (size_t)NNODES * FIN) {
        float4 v0 = *(const float4*)(x + e);
        float4 v1 = *(const float4*)(x + e + 4);
        o[0] = f2bf(v0.x); o[1] = f2bf(v0.y); o[2] = f2bf(v0.z); o[3] = f2bf(v0.w);
        o[4] = f2bf(v1.x); o[5] = f2bf(v1.y); o[6] = f2bf(v1.z); o[7] = f2bf(v1.w);
    } else {
        o = (bf16x8)0;
    }
    *(bf16x8*)(xb + e) = o;
}

__global__ void k_cvt_wt(const float* __restrict__ W, unsigned short* __restrict__ Wt, int K) {
    int t = blockIdx.x * 256 + threadIdx.x;
    if (t >= 512 * K) return;
    int n = t / K, k = t - n * K;
    Wt[t] = f2bf(W[(size_t)k * 512 + n]);
}

// ---------------- CSR build ----------------

__global__ void k_deg(const int* __restrict__ dst, int* __restrict__ deg) {
    int e = blockIdx.x * 256 + threadIdx.x;
    if (e < NEDGES) atomicAdd(&deg[dst[e]], 1);
}

__global__ void k_scan(const int* __restrict__ deg, int* __restrict__ off, int* __restrict__ cursor) {
    __shared__ int sh[1024];
    constexpr int CH = (NNODES + 1023) / 1024;
    int t = threadIdx.x;
    int base = t * CH;
    int vals[CH];
    int local = 0;
#pragma unroll
    for (int i = 0; i < CH; ++i) {
        int idx = base + i;
        int v = (idx < NNODES) ? deg[idx] : 0;
        vals[i] = v;
        local += v;
    }
    sh[t] = local;
    __syncthreads();
    for (int o = 1; o < 1024; o <<= 1) {
        int add = (t >= o) ? sh[t - o] : 0;
        __syncthreads();
        sh[t] += add;
        __syncthreads();
    }
    int run = sh[t] - local;
#pragma unroll
    for (int i = 0; i < CH; ++i) {
        int idx = base + i;
        if (idx < NNODES) {
            off[idx] = run;
            cursor[idx] = run;
            run += vals[i];
        }
    }
    if (t == 1023) off[NNODES] = sh[1023];
}

__global__ void k_fill(const int* __restrict__ src, const int* __restrict__ dst,
                       const float* __restrict__ ew, int* __restrict__ cursor,
                       int* __restrict__ csrc, float* __restrict__ cw) {
    int e = blockIdx.x * 256 + threadIdx.x;
    if (e < NEDGES) {
        int p = atomicAdd(&cursor[dst[e]], 1);
        csrc[p] = src[e];
        cw[p] = ew[e];
    }
}

// ---------------- aggregation (gather, bf16 in/out, fp32 accum) ----------------

__global__ void k_agg128(const unsigned short* __restrict__ xb, const int* __restrict__ off,
                         const int* __restrict__ csrc, const float* __restrict__ cw,
                         unsigned short* __restrict__ out) {
    int node = blockIdx.x * 4 + (threadIdx.x >> 6);
    if (node >= NNODES) return;
    int lane = threadIdx.x & 63;
    float a0 = 0.f, a1 = 0.f;
    int s = off[node], e = off[node + 1];
    for (int k = s; k < e; ++k) {
        int j = csrc[k];
        float w = cw[k];
        unsigned int v = *(const unsigned int*)(xb + (size_t)j * FIN + lane * 2);
        a0 += w * bf2f((unsigned short)(v & 0xFFFF));
        a1 += w * bf2f((unsigned short)(v >> 16));
    }
    unsigned int o = (unsigned int)f2bf(a0) | ((unsigned int)f2bf(a1) << 16);
    *(unsigned int*)(out + (size_t)node * FIN + lane * 2) = o;
}

__global__ void k_agg512(const unsigned short* __restrict__ h, const int* __restrict__ off,
                         const int* __restrict__ csrc, const float* __restrict__ cw,
                         unsigned short* __restrict__ out) {
    int node = blockIdx.x * 4 + (threadIdx.x >> 6);
    if (node >= NNODES) return;
    int lane = threadIdx.x & 63;
    float acc[8] = {};
    int s = off[node], e = off[node + 1];
    for (int k = s; k < e; ++k) {
        int j = csrc[k];
        float w = cw[k];
        bf16x8 a = *(const bf16x8*)(h + (size_t)j * HID + lane * 8);
#pragma unroll
        for (int q = 0; q < 8; ++q)
            acc[q] += w * bf2f((unsigned short)a[q]);
    }
    bf16x8 o;
#pragma unroll
    for (int q = 0; q < 8; ++q) o[q] = (short)f2bf(acc[q]);
    *(bf16x8*)(out + (size_t)node * HID + lane * 8) = o;
}

// ---------------- dual MFMA GEMM: C = relu(A0@B0 + A1@B1 + bias) ----------------
// A: [MPAD][K] bf16; Bt: [512][K] bf16 (pre-transposed). 128x128 tile, BK=32,
// 4 waves (2x2 of 64x64), 4x4 16x16x32 frags/wave.
// Double-buffered LDS pipeline: STAGE(next) -> compute(cur) -> syncthreads
// (compiler's vmcnt(0) drain before s_barrier lands after compute => loads fly
// under MFMA). LDS k-slot XOR-swizzle p = s ^ ((row>>1)&3), applied on BOTH
// the per-lane global source (linear gload_lds dest) and the ds_read index.
// 1D grid, col in low 2 bits so the 4 blocks sharing an A panel co-dispatch.

template <int K, bool POOL>
__global__ __launch_bounds__(256)
void k_mfma_dual(const unsigned short* __restrict__ A0, const unsigned short* __restrict__ B0t,
                 const unsigned short* __restrict__ A1, const unsigned short* __restrict__ B1t,
                 const float* __restrict__ bias,
                 unsigned short* __restrict__ C,
                 const int* __restrict__ batch, float* __restrict__ psum) {
    constexpr int KT = K / 32;       // K-tiles per matrix
    constexpr int NT = 2 * KT;       // total tiles (two matrices)
    __shared__ unsigned short As[2][128 * 32];
    __shared__ unsigned short Bs[2][128 * 32];
    int tid = threadIdx.x;
    int l = tid & 63, w = tid >> 6;
    int wr = w >> 1, wc = w & 1;
    int bid = blockIdx.x;
    int row0 = (bid >> 2) * 128;
    int col0 = (bid & 3) * 128;
    int lr = l & 15, hi = l >> 4;
    int pofs = (hi ^ ((lr >> 1) & 3)) * 8;   // swizzled k-slot offset (ushorts)

    // staging chunk geometry: chunk c in [0,512), r=c>>2, p=c&3,
    // global slot g = p ^ ((r>>1)&3); LDS dest linear at c*16 bytes.
    int c0 = tid, c1 = tid + 256;
    int r0 = c0 >> 2, g0 = (c0 & 3) ^ ((r0 >> 1) & 3);
    int r1 = c1 >> 2, g1 = (c1 & 3) ^ ((r1 >> 1) & 3);

    const unsigned short* Amat[2] = {A0, A1};
    const unsigned short* Bmat[2] = {B0t, B1t};

    auto stage = [&](int t, int buf) {
        int mat = t / KT;
        int k0 = (t - mat * KT) * 32;
        const unsigned short* A = Amat[mat];
        const unsigned short* Bt = Bmat[mat];
        gload_lds16(A + (size_t)(row0 + r0) * K + k0 + g0 * 8, &As[buf][c0 * 8]);
        gload_lds16(A + (size_t)(row0 + r1) * K + k0 + g1 * 8, &As[buf][c1 * 8]);
        gload_lds16(Bt + (size_t)(col0 + r0) * K + k0 + g0 * 8, &Bs[buf][c0 * 8]);
        gload_lds16(Bt + (size_t)(col0 + r1) * K + k0 + g1 * 8, &Bs[buf][c1 * 8]);
    };

    f32x4 acc[4][4];
#pragma unroll
    for (int m = 0; m < 4; ++m)
#pragma unroll
        for (int n = 0; n < 4; ++n) acc[m][n] = (f32x4)0.f;

    stage(0, 0);
    __syncthreads();

    int cur = 0;
    for (int t = 0; t < NT; ++t) {
        if (t + 1 < NT) stage(t + 1, cur ^ 1);
        const unsigned short* Ab = &As[cur][0];
        const unsigned short* Bb = &Bs[cur][0];
        bf16x8 af[4], bfr[4];
#pragma unroll
        for (int m = 0; m < 4; ++m)
            af[m] = *(const bf16x8*)&Ab[(wr * 64 + m * 16 + lr) * 32 + pofs];
#pragma unroll
        for (int n = 0; n < 4; ++n)
            bfr[n] = *(const bf16x8*)&Bb[(wc * 64 + n * 16 + lr) * 32 + pofs];
#pragma unroll
        for (int m = 0; m < 4; ++m)
#pragma unroll
            for (int n = 0; n < 4; ++n)
                acc[m][n] = __builtin_amdgcn_mfma_f32_16x16x32_bf16(af[m], bfr[n], acc[m][n], 0, 0, 0);
        __syncthreads();   // drains vmcnt (next tile staged) + protects buf reuse
        cur ^= 1;
    }

    // epilogue: C/D layout col = l&15, row = (l>>4)*4 + i
    float bv[4];
#pragma unroll
    for (int n = 0; n < 4; ++n) bv[n] = bias[col0 + wc * 64 + n * 16 + lr];
    int rbase = row0 + wr * 64 + hi * 4;

    if constexpr (!POOL) {
#pragma unroll
        for (int m = 0; m < 4; ++m) {
#pragma unroll
            for (int i = 0; i < 4; ++i) {
                int r = rbase + m * 16 + i;
                if (r < NNODES) {
#pragma unroll
                    for (int n = 0; n < 4; ++n) {
                        int col = col0 + wc * 64 + n * 16 + lr;
                        C[(size_t)r * HID + col] = f2bf(fmaxf(acc[m][n][i] + bv[n], 0.f));
                    }
                }
            }
        }
    } else {
#pragma unroll
        for (int m = 0; m < 4; ++m) {
            int b[4];
#pragma unroll
            for (int i = 0; i < 4; ++i) {
                int r = rbase + m * 16 + i;
                b[i] = (r < NNODES) ? batch[r] : -1;
            }
#pragma unroll
            for (int n = 0; n < 4; ++n) {
                int col = col0 + wc * 64 + n * 16 + lr;
                int cb = -1;
                float run = 0.f;
#pragma unroll
                for (int i = 0; i < 4; ++i) {
                    if (b[i] >= 0) {
                        float v = fmaxf(acc[m][n][i] + bv[n], 0.f);
                        if (b[i] == cb) {
                            run += v;
                        } else {
                            if (cb >= 0) atomicAdd(&psum[(size_t)cb * HID + col], run);
                            cb = b[i];
                            run = v;
                        }
                    }
                }
                if (cb >= 0) atomicAdd(&psum[(size_t)cb * HID + col], run);
            }
        }
    }
}

// ---------------- pooling count (LDS histogram) + MLP head (fp32) ----------------

__global__ void k_cnt(const int* __restrict__ batch, float* __restrict__ cnt) {
    __shared__ int h[NGRAPH];
    int t = threadIdx.x;
    if (t < NGRAPH) h[t] = 0;
    __syncthreads();
    int i = blockIdx.x * 256 + t;
    if (i < NNODES) atomicAdd(&h[batch[i]], 1);
    __syncthreads();
    if (t < NGRAPH && h[t] != 0) atomicAdd(&cnt[t], (float)h[t]);
}

__global__ void k_head(const float* __restrict__ psum, const float* __restrict__ cnt,
                       const float* __restrict__ W1, const float* __restrict__ b1,
                       const float* __restrict__ W2, const float* __restrict__ b2,
                       const float* __restrict__ W3, const float* __restrict__ b3,
                       float* __restrict__ out) {
    __shared__ float pooled[HID];
    __shared__ float o1[64];
    __shared__ float o2[16];
    int g = blockIdx.x, t = threadIdx.x;
    float c = fmaxf(cnt[g], 1.0f);
    for (int k = t; k < HID; k += 64) pooled[k] = psum[(size_t)g * HID + k] / c;
    __syncthreads();
    float a = b1[t];
    for (int k = 0; k < HID; ++k) a += pooled[k] * W1[k * 64 + t];
    o1[t] = fmaxf(a, 0.f);
    __syncthreads();
    if (t < 16) {
        float a2 = b2[t];
        for (int k = 0; k < 64; ++k) a2 += o1[k] * W2[k * 16 + t];
        o2[t] = fmaxf(a2, 0.f);
    }
    __syncthreads();
    if (t == 0) {
        float a3 = b3[0];
        for (int k = 0; k < 16; ++k) a3 += o2[k] * W3[k];
        out[g] = a3;
    }
}

// ---------------- launch ----------------

extern "C" void kernel_launch(void* const* d_in, const int* in_sizes, int n_in,
                              void* d_out, int out_size, void* d_ws, size_t ws_size,
                              hipStream_t stream) {
    const float* x = (const float*)d_in[0];
    const int* ei = (const int*)d_in[1];
    const int* src = ei;
    const int* dst = ei + NEDGES;
    const float* ew = (const float*)d_in[2];
    const int* batch = (const int*)d_in[3];
    const float* Wr1 = (const float*)d_in[4];
    const float* br1 = (const float*)d_in[5];
    const float* Wo1 = (const float*)d_in[6];
    const float* Wr2 = (const float*)d_in[7];
    const float* br2 = (const float*)d_in[8];
    const float* Wo2 = (const float*)d_in[9];
    const float* W1 = (const float*)d_in[10];
    const float* b1 = (const float*)d_in[11];
    const float* W2 = (const float*)d_in[12];
    const float* b2 = (const float*)d_in[13];
    const float* W3 = (const float*)d_in[14];
    const float* b3 = (const float*)d_in[15];
    float* out = (float*)d_out;

    char* ws = (char*)d_ws;
    size_t o = 0;
    auto alloc = [&](size_t bytes) -> void* {
        void* p = ws + o;
        o = (o + bytes + 255) & ~(size_t)255;
        return p;
    };
    int* deg = (int*)alloc((size_t)NNODES * 4);
    int* off = (int*)alloc((size_t)(NNODES + 1) * 4);
    int* cur = (int*)alloc((size_t)NNODES * 4);
    int* csrc = (int*)alloc((size_t)NEDGES * 4);
    float* cw = (float*)alloc((size_t)NEDGES * 4);
    unsigned short* xb = (unsigned short*)alloc((size_t)MPAD * FIN * 2);
    unsigned short* agg1 = (unsigned short*)alloc((size_t)MPAD * FIN * 2);
    unsigned short* h1 = (unsigned short*)alloc((size_t)MPAD * HID * 2);
    unsigned short* agg2 = (unsigned short*)alloc((size_t)MPAD * HID * 2);
    unsigned short* Wr1t = (unsigned short*)alloc((size_t)512 * FIN * 2);
    unsigned short* Wo1t = (unsigned short*)alloc((size_t)512 * FIN * 2);
    unsigned short* Wr2t = (unsigned short*)alloc((size_t)512 * HID * 2);
    unsigned short* Wo2t = (unsigned short*)alloc((size_t)512 * HID * 2);
    float* psum = (float*)alloc((size_t)NGRAPH * HID * 4);
    float* cnt = (float*)alloc((size_t)NGRAPH * 4);

    hipMemsetAsync(deg, 0, (size_t)NNODES * 4, stream);
    hipMemsetAsync(psum, 0, (size_t)NGRAPH * HID * 4, stream);
    hipMemsetAsync(cnt, 0, (size_t)NGRAPH * 4, stream);

    // conversions
    k_cvt_x<<<(MPAD * FIN / 8 + 255) / 256, 256, 0, stream>>>(x, xb);
    k_cvt_wt<<<(512 * FIN + 255) / 256, 256, 0, stream>>>(Wr1, Wr1t, FIN);
    k_cvt_wt<<<(512 * FIN + 255) / 256, 256, 0, stream>>>(Wo1, Wo1t, FIN);
    k_cvt_wt<<<(512 * HID + 255) / 256, 256, 0, stream>>>(Wr2, Wr2t, HID);
    k_cvt_wt<<<(512 * HID + 255) / 256, 256, 0, stream>>>(Wo2, Wo2t, HID);

    // CSR
    k_deg<<<(NEDGES + 255) / 256, 256, 0, stream>>>(dst, deg);
    k_scan<<<1, 1024, 0, stream>>>(deg, off, cur);
    k_fill<<<(NEDGES + 255) / 256, 256, 0, stream>>>(src, dst, ew, cur, csrc, cw);

    // layer 1
    k_agg128<<<(NNODES + 3) / 4, 256, 0, stream>>>(xb, off, csrc, cw, agg1);
    int nblk = (MPAD / 128) * 4;   // col in low 2 bits
    k_mfma_dual<FIN, false><<<nblk, 256, 0, stream>>>(agg1, Wr1t, xb, Wo1t, br1, h1, nullptr, nullptr);

    // layer 2 (+ fused mean-pool numerator)
    k_agg512<<<(NNODES + 3) / 4, 256, 0, stream>>>(h1, off, csrc, cw, agg2);
    k_cnt<<<(NNODES + 255) / 256, 256, 0, stream>>>(batch, cnt);
    k_mfma_dual<HID, true><<<nblk, 256, 0, stream>>>(agg2, Wr2t, h1, Wo2t, br2, nullptr, batch, psum);

    // head
    k_head<<<NGRAPH, 64, 0, stream>>>(psum, cnt, W1, b1, W2, b2, W3, b3, out);
}